// Round 6
// baseline (990.767 us; speedup 1.0000x reference)
//
#include <hip/hip_runtime.h>
#include <hip/hip_bf16.h>

// MPS chain: y[b,c] over 784 sites, chi=64, d=2, 10 ch, batch 1024.
// R6: barrier-free lane-local recurrence. One wave = full 64x64 matrix x 16
// batch cols; 640 independent wave-chains (64-thr blocks, XCD-swizzled).
// Output-bond relabeling P(mt,mu) = 32*(mt>>1) + 8*(mu>>2) + 4*(mt&1) + (mu&3)
// makes the MFMA D-output (after sigmoid) IDENTICAL, lane-for-lane, to the
// next site's B-operand fragments: t-state lives entirely in VGPRs. No LDS,
// no barriers, no shuffles. A-frags: 16 x global_load_dwordx4 per site from
// frag-order wsA, ping-pong prefetch (loads float freely across sites).
// Layouts (verified R1-R5): A-op m=l&15, k=8*(l>>4)+j; B-op col=l&15, same k;
// D row=4*(l>>4)+r, col=l&15.

#define LEN 784
#define NCH 10

typedef short bf16x8 __attribute__((ext_vector_type(8)));
typedef float f32x4  __attribute__((ext_vector_type(4)));

#define WSA_SHORTS ((size_t)NCH * LEN * 8192)
#define WSX_FLOATS ((size_t)1024 * 2 * LEN)
#define WS_NEED (WSA_SHORTS * 2 + WSX_FLOATS * 4)

#define XSCALE -2.88539008177792681f   // -2*log2(e)
#define XUNDO  -0.34657359027997264f   // 1/XSCALE

static __device__ __forceinline__ unsigned short f2bf(float f) {
    union { __hip_bfloat16 h; unsigned short s; } u;
    u.h = __float2bfloat16(f);
    return u.s;
}

// ---- pre-pass: tensors -> bf16 frag-order wsA (P-permuted m), x -> wsX ----
__global__ __launch_bounds__(1024) void prepass(const float* __restrict__ x,
                                                const float* __restrict__ tens,
                                                short* __restrict__ wsA,
                                                float* __restrict__ wsX)
{
    const int bid = blockIdx.x;
    const int t = threadIdx.x;
    if (bid < NCH * LEN) {
        // t = [mt:4][ii:2][kf:2][lane:64] -> one 8-elem frag slice per thread
        const int mt = t >> 8, ii = (t >> 7) & 1, kf = (t >> 6) & 1, l = t & 63;
        const int l15 = l & 15;
        // P-permuted output bond: row mu=l15 of tile mt -> physical bout
        const int bout = 32 * (mt >> 1) + 8 * (l15 >> 2) + 4 * (mt & 1) + (l15 & 3);
        const int a0 = 32 * kf + 8 * (l >> 4);   // physical k (identity labeling)
        const float* src = tens + (size_t)bid * 8192;   // [a][i][bout]
        unsigned int wv[4];
        #pragma unroll
        for (int p = 0; p < 4; ++p) {
            float f0 = src[(size_t)(a0 + 2 * p) * 128 + ii * 64 + bout];
            float f1 = src[(size_t)(a0 + 2 * p + 1) * 128 + ii * 64 + bout];
            wv[p] = (unsigned)f2bf(f0) | ((unsigned)f2bf(f1) << 16);
        }
        *(int4*)(wsA + (size_t)bid * 8192 + (size_t)t * 8) = *(int4*)wv;
    } else {
        // x[b][i][n] -> wsX[b][2n+i], pre-scaled by XSCALE
        int b = bid - NCH * LEN;
        if (t < LEN) {
            float v0 = x[(size_t)b * (2 * LEN) + t] * XSCALE;
            float v1 = x[(size_t)b * (2 * LEN) + LEN + t] * XSCALE;
            float2 pk; pk.x = v0; pk.y = v1;
            *(float2*)(wsX + (size_t)b * (2 * LEN) + 2 * t) = pk;
        }
    }
}

// ---- main chain kernel: one wave per block, fully independent ----
template <bool USE_WS>
__global__ __launch_bounds__(64) void mps_fwd6(const float* __restrict__ x,
                                               const float* __restrict__ tens,
                                               const short* __restrict__ wsA,
                                               const float* __restrict__ wsX,
                                               float* __restrict__ out)
{
    const int lane = threadIdx.x;
    const int g = lane >> 4, l15 = lane & 15;

    // XCD-aware: 640 = 8 XCDs x 80 chains; each XCD sees <=2 channels
    const int p = blockIdx.x;
    const int gidx = (p & 7) * 80 + (p >> 3);
    const int ch = gidx >> 6;
    const int b0 = (gidx & 63) * 16;

    const short* asrc = wsA + (size_t)ch * LEN * 8192;
    const float* tsrc = tens + (size_t)ch * LEN * 8192;
    const float* xsrc = USE_WS ? (wsX + (size_t)(b0 + l15) * (2 * LEN))
                               : (x + (size_t)(b0 + l15) * (2 * LEN));

    // t-state in registers: tf[kf][j] = t[32kf + 8g + j] for col l15.
    // init t[a] = (a==0): only lane g==0, elem 0 of tf0.
    bf16x8 tf0, tf1;
    #pragma unroll
    for (int j = 0; j < 8; ++j) { tf0[j] = 0; tf1[j] = 0; }
    if (g == 0) tf0[0] = (short)0x3F80;

    auto loadA = [&](int site, bf16x8 (&A)[16]) {
        site = site < LEN ? site : LEN - 1;
        if (USE_WS) {
            const short* sb = asrc + (size_t)site * 8192;
            #pragma unroll
            for (int f = 0; f < 16; ++f)
                A[f] = *(const bf16x8*)(sb + f * 512 + lane * 8);
        } else {
            const float* sb = tsrc + (size_t)site * 8192;
            #pragma unroll
            for (int f = 0; f < 16; ++f) {
                int mt = f >> 2, ii = (f >> 1) & 1, kf = f & 1;
                int bout = 32 * (mt >> 1) + 8 * (l15 >> 2) + 4 * (mt & 1) + (l15 & 3);
                int a0 = 32 * kf + 8 * g;
                unsigned int wv[4];
                #pragma unroll
                for (int q2 = 0; q2 < 4; ++q2) {
                    float f0 = sb[(size_t)(a0 + 2 * q2) * 128 + ii * 64 + bout];
                    float f1 = sb[(size_t)(a0 + 2 * q2 + 1) * 128 + ii * 64 + bout];
                    wv[q2] = (unsigned)f2bf(f0) | ((unsigned)f2bf(f1) << 16);
                }
                A[f] = *(bf16x8*)wv;
            }
        }
    };

    auto loadX = [&](int nb, float4& qa, float4& qb) {
        nb = nb <= LEN - 4 ? nb : LEN - 4;
        if (USE_WS) {
            qa = *(const float4*)(xsrc + 2 * nb);
            qb = *(const float4*)(xsrc + 2 * nb + 4);
        } else {
            float4 xi0 = *(const float4*)(xsrc + nb);
            float4 xi1 = *(const float4*)(xsrc + LEN + nb);
            qa.x = xi0.x * XSCALE; qa.y = xi1.x * XSCALE;
            qa.z = xi0.y * XSCALE; qa.w = xi1.y * XSCALE;
            qb.x = xi0.z * XSCALE; qb.y = xi1.z * XSCALE;
            qb.z = xi0.w * XSCALE; qb.w = xi1.w * XSCALE;
        }
    };

    auto body = [&](int n, bf16x8 (&Ac)[16], bf16x8 (&An)[16], float x0s, float x1s) {
        loadA(n + 1, An);   // prefetch; no barriers -> stays in flight to use

        f32x4 acc[4][2];    // [mt][ii]
        #pragma unroll
        for (int mt = 0; mt < 4; ++mt)
            #pragma unroll
            for (int ii = 0; ii < 2; ++ii)
                acc[mt][ii] = (f32x4){0.f, 0.f, 0.f, 0.f};

        #pragma unroll
        for (int kf = 0; kf < 2; ++kf) {
            bf16x8 tfk = kf ? tf1 : tf0;
            #pragma unroll
            for (int mt = 0; mt < 4; ++mt)
                #pragma unroll
                for (int ii = 0; ii < 2; ++ii)
                    acc[mt][ii] = __builtin_amdgcn_mfma_f32_16x16x32_bf16(
                        Ac[mt * 4 + ii * 2 + kf], tfk, acc[mt][ii], 0, 0, 0);
        }

        if (n == LEN - 1) {
            // physical bout 0 = P(0,0) -> mt=0, g=0, r=0; no activation; undo scale
            if (g == 0) {
                float v = (x0s * acc[0][0][0] + x1s * acc[0][1][0]) * XUNDO;
                out[(size_t)(b0 + l15) * NCH + ch] = v;
            }
        } else {
            unsigned pk[8];   // [mt][rpair]
            bool masked = (n < 5) | (n > 777);
            if (masked) {
                int e1 = (n + 1) < 6 ? (1 << (n + 1)) : 64;
                int e2 = (783 - n) < 6 ? (1 << (783 - n)) : 64;
                int dout = e1 < e2 ? e1 : e2;
                #pragma unroll
                for (int mt = 0; mt < 4; ++mt) {
                    int pb = 32 * (mt >> 1) + 8 * g + 4 * (mt & 1);  // phys bout base
                    #pragma unroll
                    for (int rp = 0; rp < 2; ++rp) {
                        unsigned short sv[2];
                        #pragma unroll
                        for (int q2 = 0; q2 < 2; ++q2) {
                            int r = 2 * rp + q2;
                            float u = x0s * acc[mt][0][r] + x1s * acc[mt][1][r];
                            float sg = __builtin_amdgcn_rcpf(1.0f + exp2f(u));
                            sv[q2] = (pb + r < dout) ? f2bf(sg) : (unsigned short)0;
                        }
                        pk[mt * 2 + rp] = (unsigned)sv[0] | ((unsigned)sv[1] << 16);
                    }
                }
            } else {
                #pragma unroll
                for (int mt = 0; mt < 4; ++mt)
                    #pragma unroll
                    for (int rp = 0; rp < 2; ++rp) {
                        unsigned short sv[2];
                        #pragma unroll
                        for (int q2 = 0; q2 < 2; ++q2) {
                            int r = 2 * rp + q2;
                            float u = x0s * acc[mt][0][r] + x1s * acc[mt][1][r];
                            float sg = __builtin_amdgcn_rcpf(1.0f + exp2f(u));
                            sv[q2] = f2bf(sg);
                        }
                        pk[mt * 2 + rp] = (unsigned)sv[0] | ((unsigned)sv[1] << 16);
                    }
            }
            // tf for next site: tf0 = {s[0][0..3], s[1][0..3]}, tf1 = {s[2], s[3]}
            union { unsigned u[4]; bf16x8 v; } u0, u1;
            u0.u[0] = pk[0]; u0.u[1] = pk[1]; u0.u[2] = pk[2]; u0.u[3] = pk[3];
            u1.u[0] = pk[4]; u1.u[1] = pk[5]; u1.u[2] = pk[6]; u1.u[3] = pk[7];
            tf0 = u0.v; tf1 = u1.v;
        }
    };

    bf16x8 A0[16], A1[16];
    float4 xa, xb, xna, xnb;
    loadA(0, A0);
    loadX(0, xa, xb);

    for (int nb = 0; nb < LEN; nb += 4) {
        loadX(nb + 4, xna, xnb);
        body(nb + 0, A0, A1, xa.x, xa.y);
        body(nb + 1, A1, A0, xa.z, xa.w);
        body(nb + 2, A0, A1, xb.x, xb.y);
        body(nb + 3, A1, A0, xb.z, xb.w);
        xa = xna; xb = xnb;
    }
}

extern "C" void kernel_launch(void* const* d_in, const int* in_sizes, int n_in,
                              void* d_out, int out_size, void* d_ws, size_t ws_size,
                              hipStream_t stream) {
    (void)in_sizes; (void)n_in; (void)out_size;
    const float* x    = (const float*)d_in[0];
    const float* tens = (const float*)d_in[1];
    float* out = (float*)d_out;
    if (ws_size >= WS_NEED) {
        short* wsA = (short*)d_ws;
        float* wsX = (float*)((char*)d_ws + WSA_SHORTS * 2);
        hipLaunchKernelGGL(prepass, dim3(NCH * LEN + 1024), dim3(1024), 0, stream,
                           x, tens, wsA, wsX);
        hipLaunchKernelGGL((mps_fwd6<true>), dim3(640), dim3(64), 0, stream,
                           x, tens, wsA, wsX, out);
    } else {
        hipLaunchKernelGGL((mps_fwd6<false>), dim3(640), dim3(64), 0, stream,
                           x, tens, (const short*)nullptr, (const float*)nullptr, out);
    }
}

// Round 7
// 981.461 us; speedup vs baseline: 1.0095x; 1.0095x over previous
//
#include <hip/hip_runtime.h>
#include <hip/hip_bf16.h>

// MPS chain: y[b,c] over 784 sites, chi=64, d=2, 10 ch, batch 1024.
// R7 = R6 (barrier-free lane-local recurrence; one wave = 64x64 matrix x 16
// batch cols; P-relabeled output bond so MFMA D == next-site B-frag lane-for-
// lane; no LDS/barriers/shuffles) + three fixes:
//  1. sched_barrier(0) pins the 16 prefetch loads at body top -> real
//     double-buffer, counted vmcnt instead of per-site latency drain.
//  2. bond mask folded into wsA (prepass zeroes rows a>=dims[site]) -> no
//     mask branch in the 784-site loop (masked t entries hit zeroed A rows;
//     output-side garbage is killed by next site's zeroed rows; exact).
//  3. running A pointer.
// P(mt,mu) = 32*(mt>>1) + 8*(mu>>2) + 4*(mt&1) + (mu&3).
// Layouts (verified R1-R6): A-op m=l&15, k=8*(l>>4)+j; B-op col=l&15, same k;
// D row=4*(l>>4)+r, col=l&15.

#define LEN 784
#define NCH 10

typedef short bf16x8 __attribute__((ext_vector_type(8)));
typedef float f32x4  __attribute__((ext_vector_type(4)));

#define WSA_SHORTS ((size_t)NCH * LEN * 8192)
#define WSX_FLOATS ((size_t)1024 * 2 * LEN)
#define WS_NEED (WSA_SHORTS * 2 + WSX_FLOATS * 4)

#define XSCALE -2.88539008177792681f   // -2*log2(e)
#define XUNDO  -0.34657359027997264f   // 1/XSCALE

static __device__ __forceinline__ unsigned short f2bf(float f) {
    union { __hip_bfloat16 h; unsigned short s; } u;
    u.h = __float2bfloat16(f);
    return u.s;
}

static __device__ __forceinline__ int site_dlim(int m) {
    // input-bond dim of site m: min(2^m, 64, 2^(784-m))
    int e1 = m < 6 ? (1 << m) : 64;
    int e2 = (LEN - m) < 6 ? (1 << (LEN - m)) : 64;
    return e1 < e2 ? e1 : e2;
}

// ---- pre-pass: tensors -> bf16 frag-order wsA (P-permuted m, masked rows),
//      x -> wsX[b][2n+i] pre-scaled ----
__global__ __launch_bounds__(1024) void prepass(const float* __restrict__ x,
                                                const float* __restrict__ tens,
                                                short* __restrict__ wsA,
                                                float* __restrict__ wsX)
{
    const int bid = blockIdx.x;
    const int t = threadIdx.x;
    if (bid < NCH * LEN) {
        const int site = bid % LEN;
        const int dlim = site_dlim(site);
        // t = [mt:4][ii:2][kf:2][lane:64] -> one 8-elem frag slice per thread
        const int mt = t >> 8, ii = (t >> 7) & 1, kf = (t >> 6) & 1, l = t & 63;
        const int l15 = l & 15;
        const int bout = 32 * (mt >> 1) + 8 * (l15 >> 2) + 4 * (mt & 1) + (l15 & 3);
        const int a0 = 32 * kf + 8 * (l >> 4);   // physical input bond (identity k)
        const float* src = tens + (size_t)bid * 8192;   // [a][i][bout]
        unsigned int wv[4];
        #pragma unroll
        for (int p = 0; p < 4; ++p) {
            int aA = a0 + 2 * p, aB = a0 + 2 * p + 1;
            float f0 = (aA < dlim) ? src[(size_t)aA * 128 + ii * 64 + bout] : 0.f;
            float f1 = (aB < dlim) ? src[(size_t)aB * 128 + ii * 64 + bout] : 0.f;
            wv[p] = (unsigned)f2bf(f0) | ((unsigned)f2bf(f1) << 16);
        }
        *(int4*)(wsA + (size_t)bid * 8192 + (size_t)t * 8) = *(int4*)wv;
    } else {
        int b = bid - NCH * LEN;
        if (t < LEN) {
            float v0 = x[(size_t)b * (2 * LEN) + t] * XSCALE;
            float v1 = x[(size_t)b * (2 * LEN) + LEN + t] * XSCALE;
            float2 pk; pk.x = v0; pk.y = v1;
            *(float2*)(wsX + (size_t)b * (2 * LEN) + 2 * t) = pk;
        }
    }
}

// ---- main chain kernel: one wave per block, fully independent ----
template <bool USE_WS>
__global__ __launch_bounds__(64) void mps_fwd7(const float* __restrict__ x,
                                               const float* __restrict__ tens,
                                               const short* __restrict__ wsA,
                                               const float* __restrict__ wsX,
                                               float* __restrict__ out)
{
    const int lane = threadIdx.x;
    const int g = lane >> 4, l15 = lane & 15;

    // XCD-aware: 640 = 8 XCDs x 80 chains; each XCD sees <=2 channels
    const int p = blockIdx.x;
    const int gidx = (p & 7) * 80 + (p >> 3);
    const int ch = gidx >> 6;
    const int b0 = (gidx & 63) * 16;

    const short* asrc = wsA + (size_t)ch * LEN * 8192;
    const float* tsrc = tens + (size_t)ch * LEN * 8192;
    const float* xsrc = USE_WS ? (wsX + (size_t)(b0 + l15) * (2 * LEN))
                               : (x + (size_t)(b0 + l15) * (2 * LEN));

    // t-state in registers: tf[kf][j] = t[32kf + 8g + j] for col l15
    bf16x8 tf0, tf1;
    #pragma unroll
    for (int j = 0; j < 8; ++j) { tf0[j] = 0; tf1[j] = 0; }
    if (g == 0) tf0[0] = (short)0x3F80;

    auto loadA = [&](int site, bf16x8 (&A)[16]) {
        site = site < LEN ? site : LEN - 1;
        if (USE_WS) {
            const short* sb = asrc + (size_t)site * 8192 + lane * 8;
            #pragma unroll
            for (int f = 0; f < 16; ++f)
                A[f] = *(const bf16x8*)(sb + f * 512);
        } else {
            const int dlim = site_dlim(site);
            const float* sb = tsrc + (size_t)site * 8192;
            #pragma unroll
            for (int f = 0; f < 16; ++f) {
                int mt = f >> 2, ii = (f >> 1) & 1, kf = f & 1;
                int bout = 32 * (mt >> 1) + 8 * (l15 >> 2) + 4 * (mt & 1) + (l15 & 3);
                int a0 = 32 * kf + 8 * g;
                unsigned int wv[4];
                #pragma unroll
                for (int q2 = 0; q2 < 4; ++q2) {
                    int aA = a0 + 2 * q2, aB = aA + 1;
                    float f0 = (aA < dlim) ? sb[(size_t)aA * 128 + ii * 64 + bout] : 0.f;
                    float f1 = (aB < dlim) ? sb[(size_t)aB * 128 + ii * 64 + bout] : 0.f;
                    wv[q2] = (unsigned)f2bf(f0) | ((unsigned)f2bf(f1) << 16);
                }
                A[f] = *(bf16x8*)wv;
            }
        }
    };

    auto loadX = [&](int nb, float4& qa, float4& qb) {
        nb = nb <= LEN - 4 ? nb : LEN - 4;
        if (USE_WS) {
            qa = *(const float4*)(xsrc + 2 * nb);
            qb = *(const float4*)(xsrc + 2 * nb + 4);
        } else {
            float4 xi0 = *(const float4*)(xsrc + nb);
            float4 xi1 = *(const float4*)(xsrc + LEN + nb);
            qa.x = xi0.x * XSCALE; qa.y = xi1.x * XSCALE;
            qa.z = xi0.y * XSCALE; qa.w = xi1.y * XSCALE;
            qb.x = xi0.z * XSCALE; qb.y = xi1.z * XSCALE;
            qb.z = xi0.w * XSCALE; qb.w = xi1.w * XSCALE;
        }
    };

    auto body = [&](int n, bf16x8 (&Ac)[16], bf16x8 (&An)[16], float x0s, float x1s) {
        // (1) issue next-site loads, pinned here by a scheduling fence
        loadA(n + 1, An);
        __builtin_amdgcn_sched_barrier(0);

        // (2) 16 MFMA on current buffer
        f32x4 acc[4][2];    // [mt][ii]
        #pragma unroll
        for (int mt = 0; mt < 4; ++mt)
            #pragma unroll
            for (int ii = 0; ii < 2; ++ii)
                acc[mt][ii] = (f32x4){0.f, 0.f, 0.f, 0.f};

        #pragma unroll
        for (int kf = 0; kf < 2; ++kf) {
            bf16x8 tfk = kf ? tf1 : tf0;
            #pragma unroll
            for (int mt = 0; mt < 4; ++mt)
                #pragma unroll
                for (int ii = 0; ii < 2; ++ii)
                    acc[mt][ii] = __builtin_amdgcn_mfma_f32_16x16x32_bf16(
                        Ac[mt * 4 + ii * 2 + kf], tfk, acc[mt][ii], 0, 0, 0);
        }

        // (3) epilogue: x-combine + sigmoid -> next t frags (no masking:
        //     masked entries are killed by zeroed wsA rows next site)
        if (n == LEN - 1) {
            if (g == 0) {
                float v = (x0s * acc[0][0][0] + x1s * acc[0][1][0]) * XUNDO;
                out[(size_t)(b0 + l15) * NCH + ch] = v;
            }
        } else {
            unsigned pk[8];   // [mt][rpair]
            #pragma unroll
            for (int mt = 0; mt < 4; ++mt)
                #pragma unroll
                for (int rp = 0; rp < 2; ++rp) {
                    unsigned short sv[2];
                    #pragma unroll
                    for (int q2 = 0; q2 < 2; ++q2) {
                        int r = 2 * rp + q2;
                        float u = x0s * acc[mt][0][r] + x1s * acc[mt][1][r];
                        float sg = __builtin_amdgcn_rcpf(1.0f + exp2f(u));
                        sv[q2] = f2bf(sg);
                    }
                    pk[mt * 2 + rp] = (unsigned)sv[0] | ((unsigned)sv[1] << 16);
                }
            union { unsigned u[4]; bf16x8 v; } u0, u1;
            u0.u[0] = pk[0]; u0.u[1] = pk[1]; u0.u[2] = pk[2]; u0.u[3] = pk[3];
            u1.u[0] = pk[4]; u1.u[1] = pk[5]; u1.u[2] = pk[6]; u1.u[3] = pk[7];
            tf0 = u0.v; tf1 = u1.v;
        }
    };

    bf16x8 A0[16], A1[16];
    float4 xa, xb, xna, xnb;
    loadA(0, A0);
    loadX(0, xa, xb);

    for (int nb = 0; nb < LEN; nb += 4) {
        loadX(nb + 4, xna, xnb);
        body(nb + 0, A0, A1, xa.x, xa.y);
        body(nb + 1, A1, A0, xa.z, xa.w);
        body(nb + 2, A0, A1, xb.x, xb.y);
        body(nb + 3, A1, A0, xb.z, xb.w);
        xa = xna; xb = xnb;
    }
}

extern "C" void kernel_launch(void* const* d_in, const int* in_sizes, int n_in,
                              void* d_out, int out_size, void* d_ws, size_t ws_size,
                              hipStream_t stream) {
    (void)in_sizes; (void)n_in; (void)out_size;
    const float* x    = (const float*)d_in[0];
    const float* tens = (const float*)d_in[1];
    float* out = (float*)d_out;
    if (ws_size >= WS_NEED) {
        short* wsA = (short*)d_ws;
        float* wsX = (float*)((char*)d_ws + WSA_SHORTS * 2);
        hipLaunchKernelGGL(prepass, dim3(NCH * LEN + 1024), dim3(1024), 0, stream,
                           x, tens, wsA, wsX);
        hipLaunchKernelGGL((mps_fwd7<true>), dim3(640), dim3(64), 0, stream,
                           x, tens, wsA, wsX, out);
    } else {
        hipLaunchKernelGGL((mps_fwd7<false>), dim3(640), dim3(64), 0, stream,
                           x, tens, (const short*)nullptr, (const float*)nullptr, out);
    }
}

// Round 8
// 673.333 us; speedup vs baseline: 1.4714x; 1.4576x over previous
//
#include <hip/hip_runtime.h>
#include <hip/hip_bf16.h>

// MPS chain: y[b,c] over 784 sites, chi=64, d=2, 10 ch, batch 1024.
// R8 = R6/R7 barrier-free lane-local recurrence (one wave = 64x64 matrix x 16
// batch cols; P-relabeled output bond so MFMA D == next-site B-frag lane-for-
// lane; bond mask folded into wsA; no LDS/barriers/shuffles) with the software
// pipeline forced at machine level:
//   - ALL main-loop VMEM is inline asm (asm outputs = distinct live regs ->
//     compiler cannot collapse the multi-buffer; asm volatile order pins issue)
//   - 4 A-buffers, distance-2 prefetch (~2 bodies ~ 800 cyc cover)
//   - counted s_waitcnt vmcnt(16) per body + sched_barrier(0) (rule #18)
// Count ledger: prologue {2x,16 B0,16 B1} wait16 => x+B0 done. Group nb:
// {2x'} A:{16 B2}wait16=>B1+x' B:{16 B3}wait16=>B2 C:{16 B0}wait16=>B3
// D:{16 B1}wait16=>B0'. Invariant: consumed buffer waited one body earlier.
// P(mt,mu) = 32*(mt>>1) + 8*(mu>>2) + 4*(mt&1) + (mu&3).
// Layouts (verified R1-R7): A-op m=l&15, k=8*(l>>4)+j; B-op col=l&15, same k;
// D row=4*(l>>4)+r, col=l&15.

#define LEN 784
#define NCH 10

typedef short bf16x8 __attribute__((ext_vector_type(8)));
typedef float f32x4  __attribute__((ext_vector_type(4)));
typedef unsigned int u32x4 __attribute__((ext_vector_type(4)));

#define WSA_SHORTS ((size_t)NCH * LEN * 8192)
#define WSX_FLOATS ((size_t)1024 * 2 * LEN)
#define WS_NEED (WSA_SHORTS * 2 + WSX_FLOATS * 4)

#define XSCALE -2.88539008177792681f   // -2*log2(e)
#define XUNDO  -0.34657359027997264f   // 1/XSCALE

static __device__ __forceinline__ unsigned short f2bf(float f) {
    union { __hip_bfloat16 h; unsigned short s; } u;
    u.h = __float2bfloat16(f);
    return u.s;
}

static __device__ __forceinline__ int site_dlim(int m) {
    int e1 = m < 6 ? (1 << m) : 64;
    int e2 = (LEN - m) < 6 ? (1 << (LEN - m)) : 64;
    return e1 < e2 ? e1 : e2;
}

// ---- pre-pass: tensors -> bf16 frag-order wsA (P-permuted m, masked rows),
//      x -> wsX[b][2n+i] pre-scaled by -2*log2(e) ----
__global__ __launch_bounds__(1024) void prepass(const float* __restrict__ x,
                                                const float* __restrict__ tens,
                                                short* __restrict__ wsA,
                                                float* __restrict__ wsX)
{
    const int bid = blockIdx.x;
    const int t = threadIdx.x;
    if (bid < NCH * LEN) {
        const int site = bid % LEN;
        const int dlim = site_dlim(site);
        const int mt = t >> 8, ii = (t >> 7) & 1, kf = (t >> 6) & 1, l = t & 63;
        const int l15 = l & 15;
        const int bout = 32 * (mt >> 1) + 8 * (l15 >> 2) + 4 * (mt & 1) + (l15 & 3);
        const int a0 = 32 * kf + 8 * (l >> 4);
        const float* src = tens + (size_t)bid * 8192;   // [a][i][bout]
        unsigned int wv[4];
        #pragma unroll
        for (int p = 0; p < 4; ++p) {
            int aA = a0 + 2 * p, aB = a0 + 2 * p + 1;
            float f0 = (aA < dlim) ? src[(size_t)aA * 128 + ii * 64 + bout] : 0.f;
            float f1 = (aB < dlim) ? src[(size_t)aB * 128 + ii * 64 + bout] : 0.f;
            wv[p] = (unsigned)f2bf(f0) | ((unsigned)f2bf(f1) << 16);
        }
        *(int4*)(wsA + (size_t)bid * 8192 + (size_t)t * 8) = *(int4*)wv;
    } else {
        int b = bid - NCH * LEN;
        if (t < LEN) {
            float v0 = x[(size_t)b * (2 * LEN) + t] * XSCALE;
            float v1 = x[(size_t)b * (2 * LEN) + LEN + t] * XSCALE;
            float2 pk; pk.x = v0; pk.y = v1;
            *(float2*)(wsX + (size_t)b * (2 * LEN) + 2 * t) = pk;
        }
    }
}

// one global_load_dwordx4: dst <- mem[sbase + voff + imm]
#define GLOAD(dst, voffr, sbase, imm) \
    asm volatile("global_load_dwordx4 %0, %1, %2 offset:" #imm \
                 : "=v"(dst) : "v"(voffr), "s"(sbase))

#define WAIT16() do { \
    asm volatile("s_waitcnt vmcnt(16)" ::: "memory"); \
    __builtin_amdgcn_sched_barrier(0); \
} while (0)

// ---- main chain kernel: one wave per block, barrier-free ----
__global__ __launch_bounds__(64) void mps_fwd8(const short* __restrict__ wsA,
                                               const float* __restrict__ wsX,
                                               float* __restrict__ out)
{
    const int lane = threadIdx.x;
    const int g = lane >> 4, l15 = lane & 15;

    // XCD-aware: 640 = 8 XCDs x 80 chains; each XCD sees <=2 channels
    const int p = blockIdx.x;
    const int gidx = (p & 7) * 80 + (p >> 3);
    const int ch = gidx >> 6;
    const int b0 = (gidx & 63) * 16;

    const short* asrc = wsA + (size_t)ch * LEN * 8192;
    const float* xsrc = wsX + (size_t)(b0 + l15) * (2 * LEN);

    const int voff0 = lane * 16;          // byte offsets for f-groups
    const int voff1 = voff0 + 4096;
    const int voff2 = voff0 + 8192;
    const int voff3 = voff0 + 12288;

    // t-state in registers: tf[kf][j] = t[32kf + 8g + j] for col l15
    bf16x8 tf0, tf1;
    #pragma unroll
    for (int j = 0; j < 8; ++j) { tf0[j] = 0; tf1[j] = 0; }
    if (g == 0) tf0[0] = (short)0x3F80;

    auto loadA = [&](int site, u32x4 (&A)[16]) {
        site = site < LEN ? site : LEN - 1;
        const short* sb = asrc + (size_t)site * 8192;
        GLOAD(A[0],  voff0, sb, 0);    GLOAD(A[1],  voff0, sb, 1024);
        GLOAD(A[2],  voff0, sb, 2048); GLOAD(A[3],  voff0, sb, 3072);
        GLOAD(A[4],  voff1, sb, 0);    GLOAD(A[5],  voff1, sb, 1024);
        GLOAD(A[6],  voff1, sb, 2048); GLOAD(A[7],  voff1, sb, 3072);
        GLOAD(A[8],  voff2, sb, 0);    GLOAD(A[9],  voff2, sb, 1024);
        GLOAD(A[10], voff2, sb, 2048); GLOAD(A[11], voff2, sb, 3072);
        GLOAD(A[12], voff3, sb, 0);    GLOAD(A[13], voff3, sb, 1024);
        GLOAD(A[14], voff3, sb, 2048); GLOAD(A[15], voff3, sb, 3072);
    };

    auto loadX = [&](int nb, float4& qa, float4& qb) {
        nb = nb <= LEN - 4 ? nb : LEN - 4;
        const float* sx = xsrc + 2 * nb;
        asm volatile("global_load_dwordx4 %0, %1, off"
                     : "=v"(qa) : "v"(sx));
        asm volatile("global_load_dwordx4 %0, %1, off offset:16"
                     : "=v"(qb) : "v"(sx));
    };

    auto body = [&](int n, u32x4 (&Ac)[16], u32x4 (&Al)[16],
                    float x0s, float x1s) {
        // (1) issue distance-2 prefetch (site n+2)
        loadA(n + 2, Al);
        __builtin_amdgcn_sched_barrier(0);

        // (2) 16 MFMA on current buffer (waited one body ago)
        f32x4 acc[4][2];    // [mt][ii]
        #pragma unroll
        for (int mt = 0; mt < 4; ++mt)
            #pragma unroll
            for (int ii = 0; ii < 2; ++ii)
                acc[mt][ii] = (f32x4){0.f, 0.f, 0.f, 0.f};

        #pragma unroll
        for (int kf = 0; kf < 2; ++kf) {
            bf16x8 tfk = kf ? tf1 : tf0;
            #pragma unroll
            for (int mt = 0; mt < 4; ++mt)
                #pragma unroll
                for (int ii = 0; ii < 2; ++ii)
                    acc[mt][ii] = __builtin_amdgcn_mfma_f32_16x16x32_bf16(
                        __builtin_bit_cast(bf16x8, Ac[mt * 4 + ii * 2 + kf]),
                        tfk, acc[mt][ii], 0, 0, 0);
        }

        // (3) epilogue: x-combine + sigmoid -> next t frags (mask is in wsA)
        if (n == LEN - 1) {
            if (g == 0) {
                float v = (x0s * acc[0][0][0] + x1s * acc[0][1][0]) * XUNDO;
                out[(size_t)(b0 + l15) * NCH + ch] = v;
            }
        } else {
            unsigned pk[8];   // [mt][rpair]
            #pragma unroll
            for (int mt = 0; mt < 4; ++mt)
                #pragma unroll
                for (int rp = 0; rp < 2; ++rp) {
                    unsigned short sv[2];
                    #pragma unroll
                    for (int q2 = 0; q2 < 2; ++q2) {
                        int r = 2 * rp + q2;
                        float u = x0s * acc[mt][0][r] + x1s * acc[mt][1][r];
                        float sg = __builtin_amdgcn_rcpf(1.0f + exp2f(u));
                        sv[q2] = f2bf(sg);
                    }
                    pk[mt * 2 + rp] = (unsigned)sv[0] | ((unsigned)sv[1] << 16);
                }
            union { unsigned u[4]; bf16x8 v; } u0, u1;
            u0.u[0] = pk[0]; u0.u[1] = pk[1]; u0.u[2] = pk[2]; u0.u[3] = pk[3];
            u1.u[0] = pk[4]; u1.u[1] = pk[5]; u1.u[2] = pk[6]; u1.u[3] = pk[7];
            tf0 = u0.v; tf1 = u1.v;
        }

        // (4) counted wait: the buffer for the NEXT body is now ready
        WAIT16();
    };

    u32x4 B0[16], B1[16], B2[16], B3[16];
    float4 xa, xb, xna, xnb;

    loadX(0, xa, xb);       // 2 loads
    loadA(0, B0);           // 16
    loadA(1, B1);           // 16  -> outstanding 34
    WAIT16();               // x + B0 ready

    for (int nb = 0; nb < LEN; nb += 4) {
        loadX(nb + 4, xna, xnb);                  // +2 (waited in body A)
        body(nb + 0, B0, B2, xa.x, xa.y);
        body(nb + 1, B1, B3, xa.z, xa.w);
        body(nb + 2, B2, B0, xb.x, xb.y);
        body(nb + 3, B3, B1, xb.z, xb.w);
        xa = xna; xb = xnb;
    }
}

// ---- fallback (ws too small): R7 plain path ----
__global__ __launch_bounds__(64) void mps_fwd8_fb(const float* __restrict__ x,
                                                  const float* __restrict__ tens,
                                                  float* __restrict__ out)
{
    const int lane = threadIdx.x;
    const int g = lane >> 4, l15 = lane & 15;
    const int p = blockIdx.x;
    const int gidx = (p & 7) * 80 + (p >> 3);
    const int ch = gidx >> 6;
    const int b0 = (gidx & 63) * 16;

    const float* tsrc = tens + (size_t)ch * LEN * 8192;
    const float* xsrc = x + (size_t)(b0 + l15) * (2 * LEN);

    bf16x8 tf0, tf1;
    #pragma unroll
    for (int j = 0; j < 8; ++j) { tf0[j] = 0; tf1[j] = 0; }
    if (g == 0) tf0[0] = (short)0x3F80;

    for (int n = 0; n < LEN; ++n) {
        const int dlim = site_dlim(n);
        const float* sb = tsrc + (size_t)n * 8192;
        bf16x8 A[16];
        #pragma unroll
        for (int f = 0; f < 16; ++f) {
            int mt = f >> 2, ii = (f >> 1) & 1, kf = f & 1;
            int bout = 32 * (mt >> 1) + 8 * (l15 >> 2) + 4 * (mt & 1) + (l15 & 3);
            int a0 = 32 * kf + 8 * g;
            unsigned int wv[4];
            #pragma unroll
            for (int q2 = 0; q2 < 4; ++q2) {
                int aA = a0 + 2 * q2, aB = aA + 1;
                float f0 = (aA < dlim) ? sb[(size_t)aA * 128 + ii * 64 + bout] : 0.f;
                float f1 = (aB < dlim) ? sb[(size_t)aB * 128 + ii * 64 + bout] : 0.f;
                wv[q2] = (unsigned)f2bf(f0) | ((unsigned)f2bf(f1) << 16);
            }
            A[f] = *(bf16x8*)wv;
        }
        float x0s = xsrc[n] * XSCALE, x1s = xsrc[LEN + n] * XSCALE;

        f32x4 acc[4][2];
        #pragma unroll
        for (int mt = 0; mt < 4; ++mt)
            #pragma unroll
            for (int ii = 0; ii < 2; ++ii)
                acc[mt][ii] = (f32x4){0.f, 0.f, 0.f, 0.f};
        #pragma unroll
        for (int kf = 0; kf < 2; ++kf) {
            bf16x8 tfk = kf ? tf1 : tf0;
            #pragma unroll
            for (int mt = 0; mt < 4; ++mt)
                #pragma unroll
                for (int ii = 0; ii < 2; ++ii)
                    acc[mt][ii] = __builtin_amdgcn_mfma_f32_16x16x32_bf16(
                        A[mt * 4 + ii * 2 + kf], tfk, acc[mt][ii], 0, 0, 0);
        }

        if (n == LEN - 1) {
            if (g == 0) {
                float v = (x0s * acc[0][0][0] + x1s * acc[0][1][0]) * XUNDO;
                out[(size_t)(b0 + l15) * NCH + ch] = v;
            }
        } else {
            unsigned pk[8];
            #pragma unroll
            for (int mt = 0; mt < 4; ++mt)
                #pragma unroll
                for (int rp = 0; rp < 2; ++rp) {
                    unsigned short sv[2];
                    #pragma unroll
                    for (int q2 = 0; q2 < 2; ++q2) {
                        int r = 2 * rp + q2;
                        float u = x0s * acc[mt][0][r] + x1s * acc[mt][1][r];
                        float sg = __builtin_amdgcn_rcpf(1.0f + exp2f(u));
                        sv[q2] = f2bf(sg);
                    }
                    pk[mt * 2 + rp] = (unsigned)sv[0] | ((unsigned)sv[1] << 16);
                }
            union { unsigned u[4]; bf16x8 v; } u0, u1;
            u0.u[0] = pk[0]; u0.u[1] = pk[1]; u0.u[2] = pk[2]; u0.u[3] = pk[3];
            u1.u[0] = pk[4]; u1.u[1] = pk[5]; u1.u[2] = pk[6]; u1.u[3] = pk[7];
            tf0 = u0.v; tf1 = u1.v;
        }
    }
}

extern "C" void kernel_launch(void* const* d_in, const int* in_sizes, int n_in,
                              void* d_out, int out_size, void* d_ws, size_t ws_size,
                              hipStream_t stream) {
    (void)in_sizes; (void)n_in; (void)out_size;
    const float* x    = (const float*)d_in[0];
    const float* tens = (const float*)d_in[1];
    float* out = (float*)d_out;
    if (ws_size >= WS_NEED) {
        short* wsA = (short*)d_ws;
        float* wsX = (float*)((char*)d_ws + WSA_SHORTS * 2);
        hipLaunchKernelGGL(prepass, dim3(NCH * LEN + 1024), dim3(1024), 0, stream,
                           x, tens, wsA, wsX);
        hipLaunchKernelGGL(mps_fwd8, dim3(640), dim3(64), 0, stream,
                           wsA, wsX, out);
    } else {
        hipLaunchKernelGGL(mps_fwd8_fb, dim3(640), dim3(64), 0, stream,
                           x, tens, out);
    }
}